// Round 4
// baseline (529.895 us; speedup 1.0000x reference)
//
#include <hip/hip_runtime.h>

#define CELL_F 30      // floats per cell: 2*5 + 20
#define TILE 64        // cells per (single-wave) block tile
#define HALF4 480      // float4 per tensor per tile (64*30/4)
#define TF4 960        // float4 per tile, both tensors

// ---------------- init: zero the accumulators in workspace ----------------
__global__ void init_ws_kernel(double* ws) {
    if (threadIdx.x < 8) ws[threadIdx.x] = 0.0;
}

// IoU exactly mirroring the reference arithmetic (clip-at-0, eps=1e-6)
__device__ __forceinline__ float iou_ref(const float* a, const float* b) {
    float ax1 = a[0] - a[2] * 0.5f, ay1 = a[1] - a[3] * 0.5f;
    float ax2 = a[0] + a[2] * 0.5f, ay2 = a[1] + a[3] * 0.5f;
    float bx1 = b[0] - b[2] * 0.5f, by1 = b[1] - b[3] * 0.5f;
    float bx2 = b[0] + b[2] * 0.5f, by2 = b[1] + b[3] * 0.5f;
    float iw = fmaxf(fminf(ax2, bx2) - fmaxf(ax1, bx1), 0.0f);
    float ih = fmaxf(fminf(ay2, by2) - fmaxf(ay1, by1), 0.0f);
    float inter = iw * ih;
    float area_a = fmaxf(ax2 - ax1, 0.0f) * fmaxf(ay2 - ay1, 0.0f);
    float area_b = fmaxf(bx2 - bx1, 0.0f) * fmaxf(by2 - by1, 0.0f);
    return inter / (area_a + area_b - inter + 1e-6f);
}

// ---------------- main reduction kernel ----------------
// One wave per block. Plain unit-stride dwordx4 loads -> VGPR (the proven
// 6.3 TB/s load shape), T14 issue-early/write-late: issue next tile's loads,
// compute current tile from LDS, then ds_write the staged regs (implicit
// vmcnt wait). Registers are the second buffer; LDS single-buffered.
// ws[0]=box_sse, ws[1]=obj_sse, ws[2]=noobj_sse, ws[3]=cls_sse, ws[4]=n_obj
__global__ __launch_bounds__(64) void yolo_loss_kernel(
    const float* __restrict__ gt, const float* __restrict__ pred,
    long long ncells, double* __restrict__ ws) {
    __shared__ float4 lds4[TF4];   // [0,480): gt tile, [480,960): pred tile

    const int lane = threadIdx.x;  // 0..63
    const float4* __restrict__ gt4 = (const float4*)gt;
    const float4* __restrict__ pr4 = (const float4*)pred;

    const long long ntiles = (ncells + TILE - 1) / TILE;
    const long long maxF4  = (ncells * (long long)CELL_F) >> 2;  // per-tensor f4
    const long long G      = gridDim.x;

    float box_s = 0.f, obj_s = 0.f, noobj_s = 0.f, cls_s = 0.f, cnt_s = 0.f;

    float4 st[15];   // staged tile (both tensors interleaved by slot)

    // 15 fully-coalesced unit-stride dwordx4 loads (1 KiB per instruction)
#define LOADR(T)                                                               \
    do {                                                                       \
        long long _b = (T) * (long long)HALF4;                                 \
        _Pragma("unroll")                                                      \
        for (int j = 0; j < 15; ++j) {                                         \
            int s = j * 64 + lane;                                             \
            bool isGt = (s < HALF4);                                           \
            long long g = _b + (isGt ? s : s - HALF4);                         \
            if (g >= maxF4) g = maxF4 - 1;                                     \
            st[j] = isGt ? gt4[g] : pr4[g];                                    \
        }                                                                      \
    } while (0)

#define WRITELDS()                                                             \
    do {                                                                       \
        _Pragma("unroll")                                                      \
        for (int j = 0; j < 15; ++j) lds4[j * 64 + lane] = st[j];              \
    } while (0)

    long long t0 = blockIdx.x;
    if (t0 < ntiles) {
        LOADR(t0);        // prologue
        WRITELDS();       // compiler inserts the vmcnt waits
        __syncthreads();

        for (long long t = t0; t < ntiles; t += G) {
            long long tn = t + G;
            bool hn = (tn < ntiles);            // wave-uniform
            if (hn) LOADR(tn);                  // issue-early: in flight during compute
            __builtin_amdgcn_sched_barrier(0);  // pin load issue before compute

            long long c = t * (long long)TILE + lane;
            if (c < ncells) {
                const float2* l2 = (const float2*)lds4;  // [0,960) gt, [960,1920) pred
                const int gb = 15 * lane, pb = 960 + 15 * lane;

                // floats 0..9: box0(4), conf0, box1(4), conf1
                float2 ga0 = l2[gb+0], ga1 = l2[gb+1], ga2 = l2[gb+2], ga3 = l2[gb+3], ga4 = l2[gb+4];
                float2 pa0 = l2[pb+0], pa1 = l2[pb+1], pa2 = l2[pb+2], pa3 = l2[pb+3], pa4 = l2[pb+4];
                float ga[10] = {ga0.x, ga0.y, ga1.x, ga1.y, ga2.x, ga2.y, ga3.x, ga3.y, ga4.x, ga4.y};
                float pa[10] = {pa0.x, pa0.y, pa1.x, pa1.y, pa2.x, pa2.y, pa3.x, pa3.y, pa4.x, pa4.y};

                float iou0 = iou_ref(ga + 0, pa + 0);
                float iou1 = iou_ref(ga + 5, pa + 5);
                int   idx  = (iou1 > iou0) ? 1 : 0;   // argmax, ties -> 0
                float miou = fmaxf(iou0, iou1);

                bool  obj = (ga[4] == 1.0f);
                float m   = obj ? 1.0f : 0.0f;

                float sse0 = 0.f, sse1 = 0.f;
                #pragma unroll
                for (int j = 0; j < 4; ++j) {
                    float d0 = pa[j] - ga[j];         sse0 += d0 * d0;
                    float d1 = pa[5 + j] - ga[5 + j]; sse1 += d1 * d1;
                }
                box_s += m * (idx ? sse1 : sse0);

                float pc0 = pa[4], pc1 = pa[9];
                float pcr = idx ? pc1 : pc0;   // responsible box conf
                float pco = idx ? pc0 : pc1;   // other box conf
                float dr  = pcr - miou;
                obj_s   += m * dr * dr;
                noobj_s += obj ? (pco * pco) : (pc0 * pc0 + pc1 * pc1);

                // floats 10..29: classes (f2 slots 5..14)
                float cs = 0.f;
                #pragma unroll
                for (int j = 5; j < 15; ++j) {
                    float2 gv = l2[gb + j], pv = l2[pb + j];
                    float d0 = pv.x - gv.x, d1 = pv.y - gv.y;
                    cs += d0 * d0 + d1 * d1;
                }
                cls_s += m * cs;
                cnt_s += m;
            }

            __syncthreads();            // reads done before overwrite (1-wave: cheap)
            if (hn) WRITELDS();         // implicit vmcnt wait on staged loads
            __syncthreads();
        }
    }
#undef LOADR
#undef WRITELDS

    // single-wave block: 64-lane shuffle reduce, lane 0 atomics
    #pragma unroll
    for (int off = 32; off > 0; off >>= 1) {
        box_s   += __shfl_down(box_s, off);
        obj_s   += __shfl_down(obj_s, off);
        noobj_s += __shfl_down(noobj_s, off);
        cls_s   += __shfl_down(cls_s, off);
        cnt_s   += __shfl_down(cnt_s, off);
    }
    if (lane == 0) {
        atomicAdd(&ws[0], (double)box_s);
        atomicAdd(&ws[1], (double)obj_s);
        atomicAdd(&ws[2], (double)noobj_s);
        atomicAdd(&ws[3], (double)cls_s);
        atomicAdd(&ws[4], (double)cnt_s);
    }
}

// ---------------- finalize: compute the 3 outputs ----------------
__global__ void finalize_kernel(const double* __restrict__ ws,
                                float* __restrict__ out, double ncells) {
    if (threadIdx.x == 0 && blockIdx.x == 0) {
        double cnt   = ws[4];
        double nobj  = fmax(cnt, 1.0);
        double nno   = fmax(2.0 * ncells - cnt, 1.0);  // n_noobj = 2*cells - n_obj
        double box   = ws[0], objl = ws[1], noobj = ws[2], cls = ws[3];
        out[0] = (float)(5.0 * box / (nobj * 4.0));          // LAMBDA_COORD * box_loss
        out[1] = (float)(0.5 * noobj / nno + objl / nobj);   // LAMBDA_NOOBJ*noobj + obj
        out[2] = (float)(cls / (nobj * 20.0));               // cls_loss
    }
}

extern "C" void kernel_launch(void* const* d_in, const int* in_sizes, int n_in,
                              void* d_out, int out_size, void* d_ws, size_t ws_size,
                              hipStream_t stream) {
    const float* gt   = (const float*)d_in[0];
    const float* pred = (const float*)d_in[1];
    float* out = (float*)d_out;
    double* ws = (double*)d_ws;

    long long ncells = (long long)in_sizes[0] / CELL_F;
    long long ntiles = (ncells + TILE - 1) / TILE;

    init_ws_kernel<<<1, 64, 0, stream>>>(ws);

    // LDS 15,360 B/block -> 10 single-wave blocks/CU x 256 CU = 2560 resident
    long long blocks = 2560;
    if (ntiles < blocks) blocks = ntiles;
    yolo_loss_kernel<<<(int)blocks, 64, 0, stream>>>(gt, pred, ncells, ws);

    finalize_kernel<<<1, 64, 0, stream>>>(ws, out, (double)ncells);
}

// Round 7
// 494.138 us; speedup vs baseline: 1.0724x; 1.0724x over previous
//
#include <hip/hip_runtime.h>

#define CELL_F 30      // floats per cell: 2*5 + 20
#define TILE 64        // cells per (single-wave) block tile
#define HALF4 480      // float4 per tensor per tile (64*30/4)
#define TF4 960        // float4 per tile, both tensors

// ---------------- init: zero the accumulators in workspace ----------------
__global__ void init_ws_kernel(double* ws) {
    if (threadIdx.x < 8) ws[threadIdx.x] = 0.0;
}

// IoU exactly mirroring the reference arithmetic (clip-at-0, eps=1e-6)
__device__ __forceinline__ float iou_ref(const float* a, const float* b) {
    float ax1 = a[0] - a[2] * 0.5f, ay1 = a[1] - a[3] * 0.5f;
    float ax2 = a[0] + a[2] * 0.5f, ay2 = a[1] + a[3] * 0.5f;
    float bx1 = b[0] - b[2] * 0.5f, by1 = b[1] - b[3] * 0.5f;
    float bx2 = b[0] + b[2] * 0.5f, by2 = b[1] + b[3] * 0.5f;
    float iw = fmaxf(fminf(ax2, bx2) - fmaxf(ax1, bx1), 0.0f);
    float ih = fmaxf(fminf(ay2, by2) - fmaxf(ay1, by1), 0.0f);
    float inter = iw * ih;
    float area_a = fmaxf(ax2 - ax1, 0.0f) * fmaxf(ay2 - ay1, 0.0f);
    float area_b = fmaxf(bx2 - bx1, 0.0f) * fmaxf(by2 - by1, 0.0f);
    return inter / (area_a + area_b - inter + 1e-6f);
}

// ---------------- main reduction kernel ----------------
// One wave per block, 10 blocks/CU (LDS-limited). Plain unit-stride dwordx4
// loads to regs (the proven-6.3TB/s shape), promptly ds_write'd to LDS in two
// <=8-float4 batches so register pressure stays ~32 staged regs (NO spill,
// the round-4 failure). No inter-wave coupling: latency is hidden by the 10
// independent waves per CU, not by in-wave pipelining.
// ws[0]=box_sse, ws[1]=obj_sse, ws[2]=noobj_sse, ws[3]=cls_sse, ws[4]=n_obj
__global__ __launch_bounds__(64) void yolo_loss_kernel(
    const float* __restrict__ gt, const float* __restrict__ pred,
    long long ncells, double* __restrict__ ws) {
    __shared__ float4 lds4[TF4];   // [0,480): gt tile, [480,960): pred tile

    const int lane = threadIdx.x;  // 0..63
    const float4* __restrict__ gt4 = (const float4*)gt;
    const float4* __restrict__ pr4 = (const float4*)pred;

    const long long ntiles = (ncells + TILE - 1) / TILE;
    const long long maxF4  = (ncells * (long long)CELL_F) >> 2;  // per-tensor f4
    const long long G      = gridDim.x;

    float box_s = 0.f, obj_s = 0.f, noobj_s = 0.f, cls_s = 0.f, cnt_s = 0.f;

    for (long long t = blockIdx.x; t < ntiles; t += G) {
        const long long b = t * (long long)HALF4;

        // ---- stage batch A: slots 0..511 (gt + straddle), 8 f4 = 32 regs ----
        {
            float4 stA[8];
            #pragma unroll
            for (int j = 0; j < 8; ++j) {
                int s = j * 64 + lane;
                bool isGt = (s < HALF4);
                long long g = b + (isGt ? s : s - HALF4);
                if (g >= maxF4) g = maxF4 - 1;
                stA[j] = isGt ? gt4[g] : pr4[g];
            }
            #pragma unroll
            for (int j = 0; j < 8; ++j) lds4[j * 64 + lane] = stA[j];
        }
        // ---- stage batch B: slots 512..959 (pred), 7 f4 = 28 regs ----
        {
            float4 stB[7];
            #pragma unroll
            for (int j = 0; j < 7; ++j) {
                long long g = b + ((j + 8) * 64 + lane) - HALF4;  // all pred
                if (g >= maxF4) g = maxF4 - 1;
                stB[j] = pr4[g];
            }
            #pragma unroll
            for (int j = 0; j < 7; ++j) lds4[(j + 8) * 64 + lane] = stB[j];
        }
        __syncthreads();   // 1-wave block: compiles to lgkmcnt drain, cheap

        long long c = t * (long long)TILE + lane;
        if (c < ncells) {
            const float2* l2 = (const float2*)lds4;  // [0,960) gt, [960,1920) pred
            const int gb = 15 * lane, pb = 960 + 15 * lane;

            // floats 0..9: box0(4), conf0, box1(4), conf1
            float2 ga0 = l2[gb+0], ga1 = l2[gb+1], ga2 = l2[gb+2], ga3 = l2[gb+3], ga4 = l2[gb+4];
            float2 pa0 = l2[pb+0], pa1 = l2[pb+1], pa2 = l2[pb+2], pa3 = l2[pb+3], pa4 = l2[pb+4];
            float ga[10] = {ga0.x, ga0.y, ga1.x, ga1.y, ga2.x, ga2.y, ga3.x, ga3.y, ga4.x, ga4.y};
            float pa[10] = {pa0.x, pa0.y, pa1.x, pa1.y, pa2.x, pa2.y, pa3.x, pa3.y, pa4.x, pa4.y};

            float iou0 = iou_ref(ga + 0, pa + 0);
            float iou1 = iou_ref(ga + 5, pa + 5);
            int   idx  = (iou1 > iou0) ? 1 : 0;   // argmax, ties -> 0
            float miou = fmaxf(iou0, iou1);

            bool  obj = (ga[4] == 1.0f);
            float m   = obj ? 1.0f : 0.0f;

            float sse0 = 0.f, sse1 = 0.f;
            #pragma unroll
            for (int j = 0; j < 4; ++j) {
                float d0 = pa[j] - ga[j];         sse0 += d0 * d0;
                float d1 = pa[5 + j] - ga[5 + j]; sse1 += d1 * d1;
            }
            box_s += m * (idx ? sse1 : sse0);

            float pc0 = pa[4], pc1 = pa[9];
            float pcr = idx ? pc1 : pc0;   // responsible box conf
            float pco = idx ? pc0 : pc1;   // other box conf
            float dr  = pcr - miou;
            obj_s   += m * dr * dr;
            noobj_s += obj ? (pco * pco) : (pc0 * pc0 + pc1 * pc1);

            // floats 10..29: classes (f2 slots 5..14)
            float cs = 0.f;
            #pragma unroll
            for (int j = 5; j < 15; ++j) {
                float2 gv = l2[gb + j], pv = l2[pb + j];
                float d0 = pv.x - gv.x, d1 = pv.y - gv.y;
                cs += d0 * d0 + d1 * d1;
            }
            cls_s += m * cs;
            cnt_s += m;
        }
        __syncthreads();   // reads retired before next tile's writes
    }

    // single-wave block: 64-lane shuffle reduce, lane 0 atomics
    #pragma unroll
    for (int off = 32; off > 0; off >>= 1) {
        box_s   += __shfl_down(box_s, off);
        obj_s   += __shfl_down(obj_s, off);
        noobj_s += __shfl_down(noobj_s, off);
        cls_s   += __shfl_down(cls_s, off);
        cnt_s   += __shfl_down(cnt_s, off);
    }
    if (lane == 0) {
        atomicAdd(&ws[0], (double)box_s);
        atomicAdd(&ws[1], (double)obj_s);
        atomicAdd(&ws[2], (double)noobj_s);
        atomicAdd(&ws[3], (double)cls_s);
        atomicAdd(&ws[4], (double)cnt_s);
    }
}

// ---------------- finalize: compute the 3 outputs ----------------
__global__ void finalize_kernel(const double* __restrict__ ws,
                                float* __restrict__ out, double ncells) {
    if (threadIdx.x == 0 && blockIdx.x == 0) {
        double cnt   = ws[4];
        double nobj  = fmax(cnt, 1.0);
        double nno   = fmax(2.0 * ncells - cnt, 1.0);  // n_noobj = 2*cells - n_obj
        double box   = ws[0], objl = ws[1], noobj = ws[2], cls = ws[3];
        out[0] = (float)(5.0 * box / (nobj * 4.0));          // LAMBDA_COORD * box_loss
        out[1] = (float)(0.5 * noobj / nno + objl / nobj);   // LAMBDA_NOOBJ*noobj + obj
        out[2] = (float)(cls / (nobj * 20.0));               // cls_loss
    }
}

extern "C" void kernel_launch(void* const* d_in, const int* in_sizes, int n_in,
                              void* d_out, int out_size, void* d_ws, size_t ws_size,
                              hipStream_t stream) {
    const float* gt   = (const float*)d_in[0];
    const float* pred = (const float*)d_in[1];
    float* out = (float*)d_out;
    double* ws = (double*)d_ws;

    long long ncells = (long long)in_sizes[0] / CELL_F;
    long long ntiles = (ncells + TILE - 1) / TILE;

    init_ws_kernel<<<1, 64, 0, stream>>>(ws);

    // LDS 15,360 B/block -> 10 single-wave blocks/CU x 256 CU = 2560 resident
    long long blocks = 2560;
    if (ntiles < blocks) blocks = ntiles;
    yolo_loss_kernel<<<(int)blocks, 64, 0, stream>>>(gt, pred, ncells, ws);

    finalize_kernel<<<1, 64, 0, stream>>>(ws, out, (double)ncells);
}

// Round 8
// 466.707 us; speedup vs baseline: 1.1354x; 1.0588x over previous
//
#include <hip/hip_runtime.h>

#define CELL_F 30
#define TILE 64            // cells per wave-tile
#define TPF2 960           // float2 per tensor per tile (64*30/2)
#define CH 15              // float2 chunks per lane per tensor
#define WAVES 4            // waves per 256-thread block
#define PRE_F2 320         // float2 prefix slots per tensor per wave (64 cells * 5)
#define LDSW_F2 640        // float2 per wave region (gt + pred prefix)

// ---------------- init: zero the accumulators in workspace ----------------
__global__ void init_ws_kernel(double* ws) {
    if (threadIdx.x < 8) ws[threadIdx.x] = 0.0;
}

// IoU exactly mirroring the reference arithmetic (clip-at-0, eps=1e-6)
__device__ __forceinline__ float iou_ref(const float* a, const float* b) {
    float ax1 = a[0] - a[2] * 0.5f, ay1 = a[1] - a[3] * 0.5f;
    float ax2 = a[0] + a[2] * 0.5f, ay2 = a[1] + a[3] * 0.5f;
    float bx1 = b[0] - b[2] * 0.5f, by1 = b[1] - b[3] * 0.5f;
    float bx2 = b[0] + b[2] * 0.5f, by2 = b[1] + b[3] * 0.5f;
    float iw = fmaxf(fminf(ax2, bx2) - fmaxf(ax1, bx1), 0.0f);
    float ih = fmaxf(fminf(ay2, by2) - fmaxf(ay1, by1), 0.0f);
    float inter = iw * ih;
    float area_a = fmaxf(ax2 - ax1, 0.0f) * fmaxf(ay2 - ay1, 0.0f);
    float area_b = fmaxf(bx2 - bx1, 0.0f) * fmaxf(by2 - by1, 0.0f);
    return inter / (area_a + area_b - inter + 1e-6f);
}

// ---------------- main reduction kernel ----------------
// 256-thr blocks = 4 independent waves; each wave owns a private 5,120 B LDS
// prefix region (NO barriers in the loop). Per 64-cell tile:
//   lap1: 30 unit-stride float2 loads; cls chunks -> in-lane d^2 partials
//         ps[15] (static regs); prefix chunks (floats 0..9 of each cell,
//         always whole float2s since 30 is even) -> LDS scatter.
//   prefix phase: lane = cell; read 10+10 floats, compute IoU/masks/box/conf.
//   apply: cls_s += __shfl(m, cell_of_chunk) * ps[j]  (mask exchange, 1 shfl).
// Occupancy: 20.5 KB LDS, target >=20 waves/CU -- the round-7 wall was
// effective wave concurrency, not bytes.
// ws[0]=box, ws[1]=obj, ws[2]=noobj, ws[3]=cls, ws[4]=n_obj
__global__ __launch_bounds__(256) void yolo_loss_kernel(
    const float* __restrict__ gt, const float* __restrict__ pred,
    long long ncells, double* __restrict__ ws) {
    __shared__ float2 lpre[WAVES * LDSW_F2];   // 20,480 B
    __shared__ float  sred[WAVES][5];

    const int tid  = threadIdx.x;
    const int wid  = tid >> 6;
    const int lane = tid & 63;
    float2* wg = lpre + wid * LDSW_F2;   // [0,320): gt prefix, [320,640): pred

    const float2* __restrict__ g2 = (const float2*)gt;
    const float2* __restrict__ p2 = (const float2*)pred;

    const long long ntiles = (ncells + TILE - 1) / TILE;
    const long long maxF2  = (ncells * (long long)CELL_F) >> 1;
    const long long nwaves = (long long)gridDim.x * WAVES;
    const long long w      = (long long)blockIdx.x * WAVES + wid;

    // contiguous tile range per wave (balanced integer split)
    const long long tlo = (w * ntiles) / nwaves;
    const long long thi = ((w + 1) * ntiles) / nwaves;

    float box_s = 0.f, obj_s = 0.f, noobj_s = 0.f, cls_s = 0.f, cnt_s = 0.f;

    for (long long t = tlo; t < thi; ++t) {
        const long long b = t * (long long)TPF2;
        float ps[CH];

        // ---- lap 1: load everything unit-stride; scatter prefix; stash cls d^2
        #pragma unroll
        for (int j = 0; j < CH; ++j) {
            int s = j * 64 + lane;                 // f2 slot in tile [0,960)
            long long gi = b + s;
            if (gi >= maxF2) gi = maxF2 - 1;       // tail clamp (exact div here)
            float2 gv = g2[gi];
            float2 pv = p2[gi];
            int f0 = 2 * s;                        // tile-float idx of .x (even)
            int c  = f0 / 30;                      // owning cell [0,64)
            int o  = f0 - 30 * c;                  // even offset in cell
            float d0 = pv.x - gv.x, d1 = pv.y - gv.y;
            ps[j] = d0 * d0 + d1 * d1;             // cls partial (unused if prefix)
            if (o < 10) {                          // whole f2 is prefix
                int q = c * 5 + (o >> 1);
                wg[q] = gv;
                wg[PRE_F2 + q] = pv;
            }
        }
        asm volatile("s_waitcnt lgkmcnt(0)" ::: "memory");
        __builtin_amdgcn_sched_barrier(0);

        // ---- prefix phase: this lane's cell ----
        float m = 0.f;
        long long c = t * (long long)TILE + lane;
        if (c < ncells) {
            float ga[10], pa[10];
            #pragma unroll
            for (int q = 0; q < 5; ++q) {
                float2 gv = wg[lane * 5 + q];
                float2 pv = wg[PRE_F2 + lane * 5 + q];
                ga[2*q] = gv.x; ga[2*q+1] = gv.y;
                pa[2*q] = pv.x; pa[2*q+1] = pv.y;
            }
            float iou0 = iou_ref(ga + 0, pa + 0);
            float iou1 = iou_ref(ga + 5, pa + 5);
            int   idx  = (iou1 > iou0) ? 1 : 0;    // argmax, ties -> 0
            float miou = fmaxf(iou0, iou1);
            bool  obj  = (ga[4] == 1.0f);
            m = obj ? 1.0f : 0.0f;

            float sse0 = 0.f, sse1 = 0.f;
            #pragma unroll
            for (int j = 0; j < 4; ++j) {
                float d0 = pa[j] - ga[j];         sse0 += d0 * d0;
                float d1 = pa[5 + j] - ga[5 + j]; sse1 += d1 * d1;
            }
            box_s += m * (idx ? sse1 : sse0);

            float pc0 = pa[4], pc1 = pa[9];
            float pcr = idx ? pc1 : pc0;   // responsible box conf
            float pco = idx ? pc0 : pc1;   // other box conf
            float dr  = pcr - miou;
            obj_s   += m * dr * dr;
            noobj_s += obj ? (pco * pco) : (pc0 * pc0 + pc1 * pc1);
            cnt_s   += m;
        }

        // ---- apply: masked cls accumulation via mask shuffle ----
        #pragma unroll
        for (int j = 0; j < CH; ++j) {
            int s  = j * 64 + lane;
            int f0 = 2 * s;
            int cc = f0 / 30;
            int o  = f0 - 30 * cc;
            float mm = __shfl(m, cc);              // all lanes participate
            if (o >= 10) cls_s += mm * ps[j];
        }
    }

    // ---- wave shuffle-reduce, then one atomic set per block ----
    #pragma unroll
    for (int off = 32; off > 0; off >>= 1) {
        box_s   += __shfl_down(box_s, off);
        obj_s   += __shfl_down(obj_s, off);
        noobj_s += __shfl_down(noobj_s, off);
        cls_s   += __shfl_down(cls_s, off);
        cnt_s   += __shfl_down(cnt_s, off);
    }
    if (lane == 0) {
        sred[wid][0] = box_s;  sred[wid][1] = obj_s; sred[wid][2] = noobj_s;
        sred[wid][3] = cls_s;  sred[wid][4] = cnt_s;
    }
    __syncthreads();   // once per block, after all loops
    if (tid == 0) {
        double b = 0, o = 0, n = 0, cl = 0, cn = 0;
        for (int ww = 0; ww < WAVES; ++ww) {
            b += sred[ww][0]; o += sred[ww][1]; n += sred[ww][2];
            cl += sred[ww][3]; cn += sred[ww][4];
        }
        atomicAdd(&ws[0], b);
        atomicAdd(&ws[1], o);
        atomicAdd(&ws[2], n);
        atomicAdd(&ws[3], cl);
        atomicAdd(&ws[4], cn);
    }
}

// ---------------- finalize: compute the 3 outputs ----------------
__global__ void finalize_kernel(const double* __restrict__ ws,
                                float* __restrict__ out, double ncells) {
    if (threadIdx.x == 0 && blockIdx.x == 0) {
        double cnt   = ws[4];
        double nobj  = fmax(cnt, 1.0);
        double nno   = fmax(2.0 * ncells - cnt, 1.0);  // n_noobj = 2*cells - n_obj
        double box   = ws[0], objl = ws[1], noobj = ws[2], cls = ws[3];
        out[0] = (float)(5.0 * box / (nobj * 4.0));          // LAMBDA_COORD * box
        out[1] = (float)(0.5 * noobj / nno + objl / nobj);   // noobj + obj
        out[2] = (float)(cls / (nobj * 20.0));               // cls
    }
}

extern "C" void kernel_launch(void* const* d_in, const int* in_sizes, int n_in,
                              void* d_out, int out_size, void* d_ws, size_t ws_size,
                              hipStream_t stream) {
    const float* gt   = (const float*)d_in[0];
    const float* pred = (const float*)d_in[1];
    float* out = (float*)d_out;
    double* ws = (double*)d_ws;

    long long ncells = (long long)in_sizes[0] / CELL_F;

    init_ws_kernel<<<1, 64, 0, stream>>>(ws);

    // 2048 blocks x 256 thr = 8192 waves; 20.5 KB LDS -> 5-8 blocks/CU
    int blocks = 2048;
    yolo_loss_kernel<<<blocks, 256, 0, stream>>>(gt, pred, ncells, ws);

    finalize_kernel<<<1, 64, 0, stream>>>(ws, out, (double)ncells);
}